// Round 11
// baseline (47.704 us; speedup 1.0000x reference)
//
#include <hip/hip_runtime.h>
#include <hip/hip_bf16.h>

#define NPTS 8192
#define NB   4
#define NQI  8                    // (batch, side) pairs
#define BLK  256
#define CH   1024                 // dense queries per knn chunk
#define NCH  8                    // max chunks (worst case all valid)
#define NSL  32                   // search slices over dense ids
#define LMAX 256                  // ceil(8192/32) max dense pts per slice
#define THR  3.33f

// ctl word layout (zeroed range [0,320) by compact block 0 each call):
//   ticket1[qi] @ qi*32 (qi<8, 128 B apart)
//   ticket2 @ 256 ; meanv[8] f32 @ 288
//   psum[64] f32 @ 320 ; pcnt[64] f32 @ 384   (plain-stored before read)
//   ncnt[8] u32 @ 448                          (written by compact, NOT zeroed)
#define W_T2    256
#define W_MEAN  288
#define W_PSUM  320
#define W_PCNT  384
#define W_NCNT  448
#define OFF_PART  4096
#define OFF_DENSE (4096 + (size_t)NQI * NSL * NPTS * 4)   // part = 8 MB

__device__ __forceinline__ void load_pt(int side, int g,
    const float* __restrict__ Ps, const float* __restrict__ Pd,
    const float* __restrict__ F,  const int* __restrict__ Ms,
    const int* __restrict__ Md,
    float& x, float& y, float& z, bool& v)
{
    if (side == 0) {               // warped src
        x = Ps[3*g+0] + F[3*g+0];
        y = Ps[3*g+1] + F[3*g+1];
        z = Ps[3*g+2] + F[3*g+2];
        v = Ms[g] > 0;
    } else {                       // dst
        x = Pd[3*g+0]; y = Pd[3*g+1]; z = Pd[3*g+2];
        v = Md[g] > 0;
    }
}

// ---------------------------------------------------------------------------
// compact: 8 blocks, one per qi=(b,side). 4 rounds x 2048 pts (8/thread):
// shfl-scan of per-thread valid counts + cross-wave LDS offsets + carry ->
// deterministic dense pack dense[qi][0..n) of float4(x,y,z,|p|^2).
// Block 0 also zeroes ctl[0..320) (consumed 2 kernel boundaries later).
// ---------------------------------------------------------------------------
__global__ __launch_bounds__(BLK) void compact_kernel(
    const float* __restrict__ Ps, const float* __restrict__ Pd,
    const float* __restrict__ F,  const int* __restrict__ Ms,
    const int* __restrict__ Md,   float4* __restrict__ dense,
    unsigned* __restrict__ ctl)
{
    const int qi = blockIdx.x, b = qi >> 1, side = qi & 1;
    const int tid = threadIdx.x, lane = tid & 63, w = tid >> 6;
    __shared__ int wc[4];

    if (qi == 0)
        for (int i = tid; i < 320; i += BLK) ctl[i] = 0;

    int carry = 0;
    for (int rnd = 0; rnd < 4; ++rnd) {
        float xx[8], yy[8], zz[8]; bool vv[8];
#pragma unroll
        for (int r = 0; r < 8; ++r) {
            const int g = b * NPTS + rnd * 2048 + r * BLK + tid;
            load_pt(side, g, Ps, Pd, F, Ms, Md, xx[r], yy[r], zz[r], vv[r]);
        }
        int c = 0;
#pragma unroll
        for (int r = 0; r < 8; ++r) c += vv[r];
        int p = c;
#pragma unroll
        for (int o = 1; o < 64; o <<= 1) {
            int t = __shfl_up(p, o);
            if (lane >= o) p += t;
        }
        if (lane == 63) wc[w] = p;
        __syncthreads();
        int base = carry + (p - c);
        int total = 0;
#pragma unroll
        for (int i = 0; i < 4; ++i) {
            if (i < w) base += wc[i];
            total += wc[i];
        }
#pragma unroll
        for (int r = 0; r < 8; ++r)
            if (vv[r]) {
                dense[(size_t)qi * NPTS + base] =
                    make_float4(xx[r], yy[r], zz[r],
                        fmaf(xx[r], xx[r], fmaf(yy[r], yy[r], zz[r] * zz[r])));
                ++base;
            }
        carry += total;
        __syncthreads();               // wc reused next round
    }
    if (tid == 0) ctl[W_NCNT + qi] = (unsigned)carry;
}

// ---------------------------------------------------------------------------
// knn: block = (chunk qc, slice sl, dir, b). Stage <=256 dense search pts
// (encode 2x,2y,2z,-|s|^2 on the fly, 4 KB LDS), 4 dense queries/thread in
// regs, broadcast inner loop (3 FMA + 1 max per pair), plain-store maxima.
// ---------------------------------------------------------------------------
__global__ __launch_bounds__(BLK) void knn_kernel(
    const float4* __restrict__ dense, const unsigned* __restrict__ ctl,
    float* __restrict__ part)
{
    const int b = blockIdx.z, dir = blockIdx.y;
    const int qc = blockIdx.x / NSL, sl = blockIdx.x % NSL;
    const int qi = b * 2 + dir, si = qi ^ 1;
    const int tid = threadIdx.x;

    const int nq = (int)ctl[W_NCNT + qi];
    const int ns = (int)ctl[W_NCNT + si];
    if (qc * CH >= nq) return;                     // block-uniform
    const int L = (ns + NSL - 1) / NSL;
    const int start = sl * L;
    int len = ns - start; if (len > L) len = L;
    if (len <= 0) return;                          // block-uniform

    __shared__ float4 sp[LMAX];
    if (tid < len) {
        const float4 p = dense[(size_t)si * NPTS + start + tid];
        sp[tid] = make_float4(2.f * p.x, 2.f * p.y, 2.f * p.z, -p.w);
    }
    __syncthreads();

    float qx[4], qy[4], qz[4], bt[4]; bool qv[4];
#pragma unroll
    for (int k = 0; k < 4; ++k) {
        const int q = qc * CH + k * BLK + tid;
        qv[k] = q < nq;
        const float4 p = dense[(size_t)qi * NPTS + (qv[k] ? q : 0)];
        qx[k] = p.x; qy[k] = p.y; qz[k] = p.z;
        bt[k] = -1e30f;
    }

#pragma unroll 4
    for (int j = 0; j < len; ++j) {
        const float4 s = sp[j];                    // wave-uniform -> broadcast
#pragma unroll
        for (int k = 0; k < 4; ++k) {
            float t = fmaf(qx[k], s.x, s.w);
            t = fmaf(qy[k], s.y, t);
            t = fmaf(qz[k], s.z, t);
            bt[k] = fmaxf(bt[k], t);
        }
    }

    float* pb = part + ((size_t)qi * NSL + sl) * NPTS;
#pragma unroll
    for (int k = 0; k < 4; ++k)
        if (qv[k]) pb[qc * CH + k * BLK + tid] = bt[k];   // coalesced
}

// ---------------------------------------------------------------------------
// final: 64 blocks = (chunk qc, dir, b). Max over NSL coalesced planes,
// d = |q|^2 - t clamped, threshold, block-reduce, shallow 2-level ticket
// (depth 8 per qi, then depth 8) -> out[0]. Only scalar intra-kernel handoff.
// ---------------------------------------------------------------------------
__global__ __launch_bounds__(BLK) void final_kernel(
    const float4* __restrict__ dense, const float* __restrict__ part,
    unsigned* __restrict__ ctl, float* __restrict__ out)
{
    const int b = blockIdx.z, dir = blockIdx.y, qc = blockIdx.x;
    const int qi = b * 2 + dir;
    const int tid = threadIdx.x, lane = tid & 63, w = tid >> 6;
    __shared__ float red[8];

    const int nq = (int)ctl[W_NCNT + qi];
    float s = 0.f, c = 0.f;
    if (qc * CH < nq) {                            // block-uniform
        const float* pr = part + (size_t)qi * NSL * NPTS;
#pragma unroll
        for (int k = 0; k < 4; ++k) {
            const int q = qc * CH + k * BLK + tid;
            if (q < nq) {
                float m = -1e30f;
#pragma unroll
                for (int sl = 0; sl < NSL; ++sl)
                    m = fmaxf(m, pr[(size_t)sl * NPTS + q]);   // coalesced
                const float qw = dense[(size_t)qi * NPTS + q].w;
                const float dd = fmaxf(qw - m, 0.f);
                if (dd < THR) { s += dd; c += 1.f; }
            }
        }
    }
#pragma unroll
    for (int off = 32; off; off >>= 1) {
        s += __shfl_down(s, off);
        c += __shfl_down(c, off);
    }
    if (lane == 0) { red[w] = s; red[4 + w] = c; }
    __syncthreads();
    if (tid == 0) {
        float* psum  = (float*)(ctl + W_PSUM);
        float* pcnt  = (float*)(ctl + W_PCNT);
        float* meanv = (float*)(ctl + W_MEAN);
        psum[qi * NCH + qc] = red[0] + red[1] + red[2] + red[3];
        pcnt[qi * NCH + qc] = red[4] + red[5] + red[6] + red[7];
        const unsigned r1 = __hip_atomic_fetch_add(&ctl[qi * 32], 1u,
                               __ATOMIC_ACQ_REL, __HIP_MEMORY_SCOPE_AGENT);
        if (r1 == NCH - 1) {               // last chunk of this qi
            float S = 0.f, C = 0.f;
#pragma unroll
            for (int g = 0; g < NCH; ++g) {
                S += psum[qi * NCH + g];
                C += pcnt[qi * NCH + g];
            }
            meanv[qi] = S / C;
            const unsigned r2 = __hip_atomic_fetch_add(&ctl[W_T2], 1u,
                                   __ATOMIC_ACQ_REL, __HIP_MEMORY_SCOPE_AGENT);
            if (r2 == NQI - 1) {           // very last qi
                float a = 0.f;
#pragma unroll
                for (int i = 0; i < NQI; ++i) a += meanv[i];
                out[0] = a;
            }
        }
    }
}

extern "C" void kernel_launch(void* const* d_in, const int* in_sizes, int n_in,
                              void* d_out, int out_size, void* d_ws, size_t ws_size,
                              hipStream_t stream)
{
    const float* Ps = (const float*)d_in[0];   // points_src  [B,N,3]
    const float* Pd = (const float*)d_in[1];   // points_dst  [B,N,3]
    const float* F  = (const float*)d_in[2];   // flows_pred  [B,N,3]
    // d_in[3] = flows_gt (unused by reference)
    const int* Ms = (const int*)d_in[4];       // masks_src [B,N]
    const int* Md = (const int*)d_in[5];       // masks_dst [B,N]
    float* out = (float*)d_out;

    unsigned* ctl = (unsigned*)d_ws;
    float* part = (float*)((char*)d_ws + OFF_PART);
    float4* dense = (float4*)((char*)d_ws + OFF_DENSE);

    compact_kernel<<<dim3(NQI), BLK, 0, stream>>>(Ps, Pd, F, Ms, Md, dense, ctl);

    knn_kernel<<<dim3(NCH * NSL, 2, NB), BLK, 0, stream>>>(dense, ctl, part);

    final_kernel<<<dim3(NCH, 2, NB), BLK, 0, stream>>>(dense, part, ctl, out);
}

// Round 12
// 33.699 us; speedup vs baseline: 1.4156x; 1.4156x over previous
//
#include <hip/hip_runtime.h>
#include <hip/hip_bf16.h>

#define NPTS 8192
#define NB   4
#define NQI  8                    // (batch, side) pairs
#define BLK  256
#define RREG 1024                 // raw points per compact region
#define NREG 8                    // regions per qi
#define QG   4                    // query groups (2 regions each) per qi
#define NSL  32                   // search slices = NREG regions x 4 subs
#define LMAX 256                  // max dense pts per slice (worst case 1024/4)
#define THR  3.33f

// ctl word layout (words; [0,320) zeroed by compact block 0 each call):
//   ticket1[qi] @ qi*32 (qi<8, 128 B apart)
//   ticket2 @ 256 ; meanv[8] f32 @ 288
//   psum[32] f32 @ 320 ; pcnt[32] f32 @ 384  (plain-stored before read)
//   bcnt[qi][reg] @ 448 + qi*8 + reg          (plain-stored by compact)
#define W_T2   256
#define W_MEAN 288
#define W_PSUM 320
#define W_PCNT 384
#define W_BCNT 448
#define OFF_PART 4096
#define OFF_PTS  (4096 + (size_t)NQI * NSL * NPTS * 4)   // part = 8 MB

__device__ __forceinline__ void load_pt(int side, int g,
    const float* __restrict__ Ps, const float* __restrict__ Pd,
    const float* __restrict__ F,  const int* __restrict__ Ms,
    const int* __restrict__ Md,
    float& x, float& y, float& z, bool& v)
{
    if (side == 0) {               // warped src
        x = Ps[3*g+0] + F[3*g+0];
        y = Ps[3*g+1] + F[3*g+1];
        z = Ps[3*g+2] + F[3*g+2];
        v = Ms[g] > 0;
    } else {                       // dst
        x = Pd[3*g+0]; y = Pd[3*g+1]; z = Pd[3*g+2];
        v = Md[g] > 0;
    }
}

// ---------------------------------------------------------------------------
// compact: 64 blocks = (region r, side, b). 1024 raw pts (4/thread), one
// ballot-scan round, pack valid pts at region base r*RREG as (x,y,z,|p|^2).
// Block (0,0,0) zeroes ctl[0,320) (consumed 2 kernel boundaries later).
// ---------------------------------------------------------------------------
__global__ __launch_bounds__(BLK) void compact_kernel(
    const float* __restrict__ Ps, const float* __restrict__ Pd,
    const float* __restrict__ F,  const int* __restrict__ Ms,
    const int* __restrict__ Md,   float4* __restrict__ pts,
    unsigned* __restrict__ ctl)
{
    const int b = blockIdx.z, side = blockIdx.y, r = blockIdx.x;
    const int qi = b * 2 + side;
    const int tid = threadIdx.x, lane = tid & 63, w = tid >> 6;
    __shared__ int wc[4];

    if (r == 0 && side == 0 && b == 0)
        for (int i = tid; i < 320; i += BLK) ctl[i] = 0;

    float xx[4], yy[4], zz[4]; bool vv[4];
#pragma unroll
    for (int k = 0; k < 4; ++k) {
        const int g = b * NPTS + r * RREG + k * BLK + tid;
        load_pt(side, g, Ps, Pd, F, Ms, Md, xx[k], yy[k], zz[k], vv[k]);
    }
    int c = 0;
#pragma unroll
    for (int k = 0; k < 4; ++k) c += vv[k];
    int p = c;
#pragma unroll
    for (int o = 1; o < 64; o <<= 1) {
        int t = __shfl_up(p, o);
        if (lane >= o) p += t;
    }
    if (lane == 63) wc[w] = p;
    __syncthreads();
    int base = p - c;
#pragma unroll
    for (int i = 0; i < 4; ++i) if (i < w) base += wc[i];
#pragma unroll
    for (int k = 0; k < 4; ++k)
        if (vv[k]) {
            pts[(size_t)qi * NPTS + r * RREG + base] =
                make_float4(xx[k], yy[k], zz[k],
                    fmaf(xx[k], xx[k], fmaf(yy[k], yy[k], zz[k] * zz[k])));
            ++base;
        }
    if (tid == 0)
        ctl[W_BCNT + qi * NREG + r] = (unsigned)(wc[0] + wc[1] + wc[2] + wc[3]);
}

// dense inner loop: KMAX queries/thread vs len staged search pts (broadcast)
template<int KMAX>
__device__ __forceinline__ void inner_loop(
    const float4* __restrict__ pts, size_t qb0, size_t qb1, int n0, int nq,
    const float4* __restrict__ sp, int len, float* __restrict__ pb, int tid)
{
    float qx[KMAX], qy[KMAX], qz[KMAX], bt[KMAX];
#pragma unroll
    for (int k = 0; k < KMAX; ++k) {
        const int q = k * BLK + tid;
        const size_t idx = (q < nq) ? (q < n0 ? qb0 + q : qb1 + (q - n0)) : qb0;
        const float4 p = pts[idx];             // coalesced float4
        qx[k] = p.x; qy[k] = p.y; qz[k] = p.z;
        bt[k] = -1e30f;
    }
#pragma unroll 4
    for (int j = 0; j < len; ++j) {
        const float4 s = sp[j];                // wave-uniform -> LDS broadcast
#pragma unroll
        for (int k = 0; k < KMAX; ++k) {
            float t = fmaf(qx[k], s.x, s.w);
            t = fmaf(qy[k], s.y, t);
            t = fmaf(qz[k], s.z, t);
            bt[k] = fmaxf(bt[k], t);
        }
    }
#pragma unroll
    for (int k = 0; k < KMAX; ++k) {
        const int q = k * BLK + tid;
        if (q < nq) pb[q] = bt[k];             // coalesced plain store
    }
}

// ---------------------------------------------------------------------------
// knn: block = (qg, sl, dir, b) = 1024 blocks. No compaction, no query LDS:
// queries = 2 packed regions read straight from L2; search slice = quarter
// of one packed region staged in 4 KB LDS (encoded 2x,2y,2z,-|s|^2).
// len<=0 blocks still store -1e30 (keeps all planes defined).
// ---------------------------------------------------------------------------
__global__ __launch_bounds__(BLK) void knn_kernel(
    const float4* __restrict__ pts, const unsigned* __restrict__ ctl,
    float* __restrict__ part)
{
    const int b = blockIdx.z, dir = blockIdx.y;
    const int qg = blockIdx.x >> 5, sl = blockIdx.x & 31;
    const int qi = b * 2 + dir, si = qi ^ 1;
    const int tid = threadIdx.x;

    const int n0 = (int)ctl[W_BCNT + qi * NREG + 2 * qg];
    const int n1 = (int)ctl[W_BCNT + qi * NREG + 2 * qg + 1];
    const int nq = n0 + n1;
    if (nq == 0) return;                       // block-uniform; no plane reads

    const int sreg = sl >> 2, sub = sl & 3;
    const int nsr = (int)ctl[W_BCNT + si * NREG + sreg];
    const int L = (nsr + 3) >> 2;
    const int start = sub * L;
    int len = nsr - start; if (len > L) len = L; if (len < 0) len = 0;

    __shared__ float4 sp[LMAX];
    if (tid < len) {
        const float4 p = pts[(size_t)si * NPTS + sreg * RREG + start + tid];
        sp[tid] = make_float4(2.f * p.x, 2.f * p.y, 2.f * p.z, -p.w);
    }
    __syncthreads();

    const size_t qb0 = (size_t)qi * NPTS + (size_t)(2 * qg) * RREG;
    const size_t qb1 = qb0 + RREG;
    float* pb = part + ((size_t)qi * NSL + sl) * NPTS + (size_t)qg * (2 * RREG);

    switch ((nq + BLK - 1) >> 8) {             // block-uniform KMAX dispatch
        case 1: inner_loop<1>(pts, qb0, qb1, n0, nq, sp, len, pb, tid); break;
        case 2: inner_loop<2>(pts, qb0, qb1, n0, nq, sp, len, pb, tid); break;
        case 3: inner_loop<3>(pts, qb0, qb1, n0, nq, sp, len, pb, tid); break;
        case 4: inner_loop<4>(pts, qb0, qb1, n0, nq, sp, len, pb, tid); break;
        case 5: inner_loop<5>(pts, qb0, qb1, n0, nq, sp, len, pb, tid); break;
        case 6: inner_loop<6>(pts, qb0, qb1, n0, nq, sp, len, pb, tid); break;
        case 7: inner_loop<7>(pts, qb0, qb1, n0, nq, sp, len, pb, tid); break;
        case 8: inner_loop<8>(pts, qb0, qb1, n0, nq, sp, len, pb, tid); break;
        default: break;
    }
}

// ---------------------------------------------------------------------------
// final: 32 blocks = (qg, dir, b). Max over 32 coalesced planes, d=|q|^2-t
// clamped, threshold, block-reduce, shallow 2-level ticket (4 then 8) -> out.
// Intra-kernel handoff limited to psum/pcnt/meanv scalars (R6-proven).
// ---------------------------------------------------------------------------
__global__ __launch_bounds__(BLK) void final_kernel(
    const float4* __restrict__ pts, const float* __restrict__ part,
    unsigned* __restrict__ ctl, float* __restrict__ out)
{
    const int b = blockIdx.z, dir = blockIdx.y, qg = blockIdx.x;
    const int qi = b * 2 + dir;
    const int tid = threadIdx.x, lane = tid & 63, w = tid >> 6;
    __shared__ float red[8];

    const int n0 = (int)ctl[W_BCNT + qi * NREG + 2 * qg];
    const int n1 = (int)ctl[W_BCNT + qi * NREG + 2 * qg + 1];
    const int nq = n0 + n1;
    const size_t qb0 = (size_t)qi * NPTS + (size_t)(2 * qg) * RREG;
    const size_t qb1 = qb0 + RREG;
    const float* pr = part + (size_t)qi * NSL * NPTS + (size_t)qg * (2 * RREG);

    float s = 0.f, c = 0.f;
#pragma unroll
    for (int k = 0; k < 8; ++k) {
        const int q = k * BLK + tid;
        if (q < nq) {
            float m = -1e30f;
#pragma unroll
            for (int sl = 0; sl < NSL; ++sl)
                m = fmaxf(m, pr[(size_t)sl * NPTS + q]);   // coalesced
            const size_t idx = (q < n0) ? qb0 + q : qb1 + (q - n0);
            const float dd = fmaxf(pts[idx].w - m, 0.f);
            if (dd < THR) { s += dd; c += 1.f; }
        }
    }
#pragma unroll
    for (int off = 32; off; off >>= 1) {
        s += __shfl_down(s, off);
        c += __shfl_down(c, off);
    }
    if (lane == 0) { red[w] = s; red[4 + w] = c; }
    __syncthreads();
    if (tid == 0) {
        float* psum  = (float*)(ctl + W_PSUM);
        float* pcnt  = (float*)(ctl + W_PCNT);
        float* meanv = (float*)(ctl + W_MEAN);
        psum[qi * QG + qg] = red[0] + red[1] + red[2] + red[3];
        pcnt[qi * QG + qg] = red[4] + red[5] + red[6] + red[7];
        const unsigned r1 = __hip_atomic_fetch_add(&ctl[qi * 32], 1u,
                               __ATOMIC_ACQ_REL, __HIP_MEMORY_SCOPE_AGENT);
        if (r1 == QG - 1) {                // last group of this qi
            float S = 0.f, C = 0.f;
#pragma unroll
            for (int g = 0; g < QG; ++g) {
                S += psum[qi * QG + g];
                C += pcnt[qi * QG + g];
            }
            meanv[qi] = S / C;
            const unsigned r2 = __hip_atomic_fetch_add(&ctl[W_T2], 1u,
                                   __ATOMIC_ACQ_REL, __HIP_MEMORY_SCOPE_AGENT);
            if (r2 == NQI - 1) {           // very last qi
                float a = 0.f;
#pragma unroll
                for (int i = 0; i < NQI; ++i) a += meanv[i];
                out[0] = a;
            }
        }
    }
}

extern "C" void kernel_launch(void* const* d_in, const int* in_sizes, int n_in,
                              void* d_out, int out_size, void* d_ws, size_t ws_size,
                              hipStream_t stream)
{
    const float* Ps = (const float*)d_in[0];   // points_src  [B,N,3]
    const float* Pd = (const float*)d_in[1];   // points_dst  [B,N,3]
    const float* F  = (const float*)d_in[2];   // flows_pred  [B,N,3]
    // d_in[3] = flows_gt (unused by reference)
    const int* Ms = (const int*)d_in[4];       // masks_src [B,N]
    const int* Md = (const int*)d_in[5];       // masks_dst [B,N]
    float* out = (float*)d_out;

    unsigned* ctl = (unsigned*)d_ws;
    float* part = (float*)((char*)d_ws + OFF_PART);
    float4* pts = (float4*)((char*)d_ws + OFF_PTS);

    compact_kernel<<<dim3(NREG, 2, NB), BLK, 0, stream>>>(
        Ps, Pd, F, Ms, Md, pts, ctl);

    knn_kernel<<<dim3(QG * NSL, 2, NB), BLK, 0, stream>>>(pts, ctl, part);

    final_kernel<<<dim3(QG, 2, NB), BLK, 0, stream>>>(pts, part, ctl, out);
}